// Round 5
// baseline (399.102 us; speedup 1.0000x reference)
//
#include <hip/hip_runtime.h>
#include <stdint.h>

typedef unsigned short u16;
typedef short bf16x8 __attribute__((ext_vector_type(8)));
typedef short bf16x4 __attribute__((ext_vector_type(4)));
typedef float f32x4 __attribute__((ext_vector_type(4)));

#define NTOT   65536
#define NB     64
#define NEDGE  262144
#define H3     4096
#define LATD   512
#define NCLS_  160
#define K1     16384
#define K2     16544   // NCLS + 1024*16

static __device__ __forceinline__ u16 f2b(float f) {   // fp32 -> bf16 RNE
  uint32_t x = __float_as_uint(f);
  return (u16)((x + 0x7FFFu + ((x >> 16) & 1u)) >> 16);
}

// ---------- CSR build: histogram (+ fused Wc = Wg1@Wg2 in block 0) ----------
__global__ void k_hist(const int* __restrict__ E, int* __restrict__ cnt,
                       const float* __restrict__ Wg1, const float* __restrict__ Wg2,
                       float* __restrict__ Wc) {
  int e = blockIdx.x * 256 + threadIdx.x;
  atomicAdd(&cnt[E[NEDGE + e]], 1);
  if (blockIdx.x == 0 && threadIdx.x < 128) {
    int c = threadIdx.x >> 4, h = threadIdx.x & 15;
    float acc = 0.f;
    for (int k = 0; k < 512; ++k) acc += Wg1[c * 512 + k] * Wg2[k * 16 + h];
    Wc[c * 16 + h] = acc;
  }
}

// ---------- exclusive scan of 65536 counts (single block, 1024 threads) ----------
__global__ __launch_bounds__(1024) void k_scan(const int* __restrict__ cnt,
                                               int* __restrict__ off,
                                               int* __restrict__ cur) {
  __shared__ int wsum[16];
  const int t = threadIdx.x;
  const int lane = t & 63, w = t >> 6;
  const int base = t << 6;                          // 64 bins per thread
  int s = 0;
  const int4* c4 = (const int4*)(cnt + base);
  #pragma unroll 4
  for (int i = 0; i < 16; ++i) { int4 v = c4[i]; s += v.x + v.y + v.z + v.w; }
  int sc = s;
  #pragma unroll
  for (int d = 1; d < 64; d <<= 1) {
    int u = __shfl_up(sc, d);
    if (lane >= d) sc += u;
  }
  if (lane == 63) wsum[w] = sc;
  __syncthreads();
  if (w == 0 && lane < 16) {
    int v = wsum[lane];
    #pragma unroll
    for (int d = 1; d < 16; d <<= 1) {
      int u = __shfl_up(v, d);
      if (lane >= d) v += u;
    }
    wsum[lane] = v;
  }
  __syncthreads();
  int run = (w == 0 ? 0 : wsum[w - 1]) + (sc - s);
  int4* o4 = (int4*)(off + base);
  int4* u4 = (int4*)(cur + base);
  #pragma unroll 4
  for (int i = 0; i < 16; ++i) {
    int4 v = c4[i];
    int4 r;
    r.x = run; run += v.x;
    r.y = run; run += v.y;
    r.z = run; run += v.z;
    r.w = run; run += v.w;
    o4[i] = r; u4[i] = r;
  }
}

// ---------- scatter edges into CSR ----------
__global__ void k_scatter(const int* __restrict__ E, int* __restrict__ cur,
                          int* __restrict__ csr) {
  int e = blockIdx.x * 256 + threadIdx.x;
  int p = atomicAdd(&cur[E[NEDGE + e]], 1);
  csr[p] = E[e];
}

// ---------- atomic-free segment sum: Out[n][c] = sum_j In[csr[j]][c] ----------
__global__ void k_gather(const int* __restrict__ off, const int* __restrict__ cnt,
                         const int* __restrict__ csr, const float* __restrict__ In,
                         float* __restrict__ Out) {
  int t = blockIdx.x * 256 + threadIdx.x;           // NTOT*8 threads
  int n = t >> 3, c = t & 7;
  int b = off[n], e = b + cnt[n];
  float acc = 0.f;
  for (int j = b; j < e; ++j) acc += In[(size_t)csr[j] * 8 + c];
  Out[(size_t)n * 8 + c] = acc;
}

// ---------- per-node: gcn out (Abuf col 160+), mix (Mbuf), cls copy ----------
__global__ void k_nodes(const float* __restrict__ S2, const float* __restrict__ Wc,
                        const float* __restrict__ X,
                        const float* __restrict__ Wbox, const float* __restrict__ bbox,
                        const float* __restrict__ Wlbl, const float* __restrict__ blbl,
                        const float* __restrict__ cls,
                        u16* __restrict__ Abuf, u16* __restrict__ Mbuf) {
  int idx = blockIdx.x * 256 + threadIdx.x;
  if (idx < NB * NCLS_) {
    int m = idx / NCLS_, i = idx - m * NCLS_;
    Abuf[(size_t)m * K2 + i] = f2b(cls[idx]);
  }
  if (idx >= NTOT * 16) return;
  int n = idx >> 4, h = idx & 15;
  int m = n >> 10, nl = n & 1023;
  const float* s2 = S2 + (size_t)n * 8;
  float xg = 0.f;
  #pragma unroll
  for (int c = 0; c < 8; ++c) xg += s2[c] * Wc[c * 16 + h];
  Abuf[(size_t)m * K2 + 160 + nl * 16 + h] = f2b(xg);
  const float* xr = X + (size_t)n * 8;
  float box = bbox[h];
  #pragma unroll
  for (int c = 0; c < 7; ++c) box += xr[1 + c] * Wbox[c * 16 + h];
  box = box > 0.f ? box : 0.f;
  float lb = xr[0] * Wlbl[h] + blbl[h];
  lb = lb > 0.f ? lb : 0.f;
  Mbuf[(size_t)m * K1 + nl * 16 + h] = f2b(box + lb);
}

// ---------- GEMM12: slab[y] = A(bf16)[64,K] @ W(fp32->bf16)[K,BN=256] ----------
// r3 version (best measured): BN=256, barrier-synced, reg-staged, 2-unrolled.
#define CVTPK(dst, lo, hi) \
  asm("v_cvt_pk_bf16_f32 %0, %1, %2" : "=v"(dst) : "v"(lo), "v"(hi))

#define MFMA_BF16 __builtin_amdgcn_mfma_f32_16x16x32_bf16

#define WPACK(I2, WwR)                                                         \
  { const int n_ = (l << 2) + (I2);                                            \
    const int sw_ = ((n_ >> 1) ^ (n_ >> 2)) & 3;                               \
    uint32_t q0, q1, q2, q3;                                                   \
    CVTPK(q0, ws0[I2], ws1[I2]);                                               \
    CVTPK(q1, ws2[I2], ws3[I2]);                                               \
    CVTPK(q2, ws4[I2], ws5[I2]);                                               \
    CVTPK(q3, ws6[I2], ws7[I2]);                                               \
    uint4 pk_ = {q0, q1, q2, q3};                                              \
    *(uint4*)(&WwR[n_ * 32 + ((wv ^ sw_) << 3)]) = pk_; }

#define WLOADS(II)                                                             \
  { const float* gw_ = gW + (size_t)(II) * stepW;                              \
    ws0 = *(const f32x4*)(gw_);                                                \
    ws1 = *(const f32x4*)(gw_ + Nw);                                           \
    ws2 = *(const f32x4*)(gw_ + 2 * Nw);                                       \
    ws3 = *(const f32x4*)(gw_ + 3 * Nw);                                       \
    ws4 = *(const f32x4*)(gw_ + 4 * Nw);                                       \
    ws5 = *(const f32x4*)(gw_ + 5 * Nw);                                       \
    ws6 = *(const f32x4*)(gw_ + 6 * Nw);                                       \
    ws7 = *(const f32x4*)(gw_ + 7 * Nw);                                       \
    aS  = *(const int4*)(gA + (size_t)(II) * 32); }

#define GEMM_STEP(ST, ArD, WrD, AwR, WwR)                                      \
  {                                                                            \
    bf16x8 a0 = *(const bf16x8*)(&ArD[foA]);                                   \
    bf16x8 a1 = *(const bf16x8*)(&ArD[foA + 512]);                             \
    bf16x8 a2 = *(const bf16x8*)(&ArD[foA + 1024]);                            \
    bf16x8 a3 = *(const bf16x8*)(&ArD[foA + 1536]);                            \
    bf16x8 b0 = *(const bf16x8*)(&WrD[foB]);                                   \
    bf16x8 b1 = *(const bf16x8*)(&WrD[foB + 512]);                             \
    bf16x8 b2 = *(const bf16x8*)(&WrD[foB + 1024]);                            \
    bf16x8 b3 = *(const bf16x8*)(&WrD[foB + 1536]);                            \
    *(int4*)(&AwR[t * 8]) = aS;                                                \
    WPACK(0, WwR) WPACK(1, WwR) WPACK(2, WwR) WPACK(3, WwR)                    \
    { const int ii = (ST) + 2 < ns ? (ST) + 2 : ns - 1;                        \
      WLOADS(ii) }                                                             \
    acc00 = MFMA_BF16(a0, b0, acc00, 0, 0, 0);                                 \
    acc01 = MFMA_BF16(a0, b1, acc01, 0, 0, 0);                                 \
    acc02 = MFMA_BF16(a0, b2, acc02, 0, 0, 0);                                 \
    acc03 = MFMA_BF16(a0, b3, acc03, 0, 0, 0);                                 \
    acc10 = MFMA_BF16(a1, b0, acc10, 0, 0, 0);                                 \
    acc11 = MFMA_BF16(a1, b1, acc11, 0, 0, 0);                                 \
    acc12 = MFMA_BF16(a1, b2, acc12, 0, 0, 0);                                 \
    acc13 = MFMA_BF16(a1, b3, acc13, 0, 0, 0);                                 \
    acc20 = MFMA_BF16(a2, b0, acc20, 0, 0, 0);                                 \
    acc21 = MFMA_BF16(a2, b1, acc21, 0, 0, 0);                                 \
    acc22 = MFMA_BF16(a2, b2, acc22, 0, 0, 0);                                 \
    acc23 = MFMA_BF16(a2, b3, acc23, 0, 0, 0);                                 \
    acc30 = MFMA_BF16(a3, b0, acc30, 0, 0, 0);                                 \
    acc31 = MFMA_BF16(a3, b1, acc31, 0, 0, 0);                                 \
    acc32 = MFMA_BF16(a3, b2, acc32, 0, 0, 0);                                 \
    acc33 = MFMA_BF16(a3, b3, acc33, 0, 0, 0);                                 \
    asm volatile("s_waitcnt lgkmcnt(0)" ::: "memory");                         \
    __builtin_amdgcn_s_barrier();                                              \
    asm volatile("" ::: "memory");                                             \
  }

__global__ __launch_bounds__(256) void k_gemm(
    const u16* __restrict__ A0, const u16* __restrict__ A1, int lda0, int lda1,
    const float* __restrict__ W0, const float* __restrict__ W1, int Nw,
    int tot0, int tot1, int per0, int per1, int slabBase1,
    float* __restrict__ Cs)
{
  __shared__ u16 lA0[2048];     // A: 64 rows x 32 k bf16, 16B-chunk XOR swizzle
  __shared__ u16 lA1[2048];
  __shared__ u16 lW0[8192];     // W^T: [n=256][k=32] bf16, sw(n) XOR on k-chunks
  __shared__ u16 lW1[8192];

  const u16* A; int lda; const float* W; int tot, per, slab;
  if (blockIdx.z == 0) { A = A0; lda = lda0; W = W0; tot = tot0; per = per0; slab = blockIdx.y; }
  else                 { A = A1; lda = lda1; W = W1; tot = tot1; per = per1; slab = slabBase1 + blockIdx.y; }

  const int n0  = blockIdx.x << 8;                  // 256-col tiles
  const int sp0 = blockIdx.y * per;
  int ns = tot - sp0; if (ns > per) ns = per;
  if (ns <= 0) return;
  const int t  = threadIdx.x;
  const int l  = t & 63;
  const int wv = t >> 6;

  // A staging: thread t -> row t>>2, 16B chunk (t&3)^swA(row); LDS linear t*8
  const int rA  = t >> 2;
  const int cAg = (t & 3) ^ ((rA >> 1) & 3);
  const u16* gA = A + (size_t)rA * lda + cAg * 8 + (size_t)sp0 * 32;

  // W staging: wave wv owns k-rows 8wv..8wv+7; lane l covers 16B at col l*4
  const float* gW = W + (size_t)(sp0 * 32 + wv * 8) * Nw + n0 + l * 4;
  const size_t stepW = (size_t)32 * Nw;

  // fragment read offsets (elements)
  const int g4 = l >> 4;
  const int li = l & 15;
  const int foA = li * 32 + ((g4 ^ ((li >> 1) & 3)) << 3);               // + rt*512
  const int foB = wv * 2048 + li * 32 +
                  ((g4 ^ (((li >> 1) ^ (li >> 2)) & 3)) << 3);           // + ct*512

  f32x4 z4 = {0.f, 0.f, 0.f, 0.f};
  f32x4 acc00 = z4, acc01 = z4, acc02 = z4, acc03 = z4;
  f32x4 acc10 = z4, acc11 = z4, acc12 = z4, acc13 = z4;
  f32x4 acc20 = z4, acc21 = z4, acc22 = z4, acc23 = z4;
  f32x4 acc30 = z4, acc31 = z4, acc32 = z4, acc33 = z4;

  f32x4 ws0, ws1, ws2, ws3, ws4, ws5, ws6, ws7;
  int4 aS;

  // ---- prologue: tile0 -> regs -> buf0; issue tile1; barrier ----
  WLOADS(0)
  *(int4*)(&lA0[t * 8]) = aS;
  WPACK(0, lW0) WPACK(1, lW0) WPACK(2, lW0) WPACK(3, lW0)
  { const int i1 = 1 < ns ? 1 : 0;
    WLOADS(i1) }
  asm volatile("s_waitcnt lgkmcnt(0)" ::: "memory");
  __builtin_amdgcn_s_barrier();
  asm volatile("" ::: "memory");

  // ---- main loop: 2-unrolled for static buffer names ----
  int st = 0;
  for (; st + 2 <= ns; st += 2) {
    GEMM_STEP(st,     lA0, lW0, lA1, lW1)
    GEMM_STEP(st + 1, lA1, lW1, lA0, lW0)
  }
  if (st < ns) {
    GEMM_STEP(st, lA0, lW0, lA1, lW1)
  }

  // store: row = rt*16 + g4*4 + j, col = n0 + wv*64 + ct*16 + li
  float* base = Cs + (size_t)slab * NB * Nw + n0 + wv * 64 + li;
  #pragma unroll
  for (int j = 0; j < 4; ++j) {
    float* r0 = base + (size_t)(g4 * 4 + j) * Nw;
    r0[0]  = acc00[j];
    r0[16] = acc01[j];
    r0[32] = acc02[j];
    r0[48] = acc03[j];
    float* r1 = r0 + 16 * Nw;
    r1[0]  = acc10[j];
    r1[16] = acc11[j];
    r1[32] = acc12[j];
    r1[48] = acc13[j];
    float* r2 = r0 + 32 * Nw;
    r2[0]  = acc20[j];
    r2[16] = acc21[j];
    r2[32] = acc22[j];
    r2[48] = acc23[j];
    float* r3 = r0 + 48 * Nw;
    r3[0]  = acc30[j];
    r3[16] = acc31[j];
    r3[32] = acc32[j];
    r3[48] = acc33[j];
  }
}

// ---------- k_gemm2: output-stationary full-K GEMM, fused bias+relu+store ----
// For GEMM3/4/5: C[64,Nw] = act(A[64,4096] @ W[4096,Nw] + b). No slabs, no
// reduction pass. BM=64 (4 waves x 16 rows), BN=32 (2 coltiles), BK=32,
// ns=128 full-K. Barrier-free: each wave privately stages the 32x32 W tile
// (4x f32x4 -> cvt_pk -> private 2KB LDS quarter), A direct global->reg.
// W is L3-resident (<=67MB); 4x wave duplication of W reads is cheap there.
#define WLOADS2(II)                                                            \
  { const float* gw_ = gW2 + (size_t)(II) * stepW2;                            \
    vs0 = *(const f32x4*)(gw_);                                                \
    vs1 = *(const f32x4*)(gw_ + Nw);                                           \
    vs2 = *(const f32x4*)(gw_ + 2 * Nw);                                       \
    vs3 = *(const f32x4*)(gw_ + 3 * Nw);                                       \
    aS2 = *(const bf16x8*)(gA2 + (size_t)(II) * 32); }

#define WPACK2(C_, Lw)                                                         \
  { uint32_t q0, q1;                                                           \
    CVTPK(q0, vs0[C_], vs1[C_]);                                               \
    CVTPK(q1, vs2[C_], vs3[C_]);                                               \
    uint2 pk_ = {q0, q1};                                                      \
    *(uint2*)(&Lw[wo2_##C_]) = pk_; }

#define GEMM2_STEP(ST, Lr, Lw)                                                 \
  {                                                                            \
    bf16x8 b0 = *(const bf16x8*)(&Lr[ro2]);                                    \
    bf16x8 b1 = *(const bf16x8*)(&Lr[ro2 + 512]);                              \
    bf16x8 a  = aC;                                                            \
    WPACK2(0, Lw) WPACK2(1, Lw) WPACK2(2, Lw) WPACK2(3, Lw)                    \
    { const int ii = (ST) + 2 < 128 ? (ST) + 2 : 127;                          \
      aC = aS2;                                                                \
      WLOADS2(ii) }                                                            \
    acc0 = MFMA_BF16(a, b0, acc0, 0, 0, 0);                                    \
    acc1 = MFMA_BF16(a, b1, acc1, 0, 0, 0);                                    \
    asm volatile("s_waitcnt lgkmcnt(0)" ::: "memory");                         \
  }

template<int WRITEF>
__global__ __launch_bounds__(256) void k_gemm2(
    const u16* __restrict__ A, const float* __restrict__ W, int Nw,
    const float* __restrict__ bias, u16* __restrict__ outb,
    float* __restrict__ outf)
{
  __shared__ u16 lB0[4096];   // 4 waves x [n=32][k=32] bf16 private quarters
  __shared__ u16 lB1[4096];
  const int t  = threadIdx.x;
  const int l  = t & 63;
  const int wv = t >> 6;
  const int g4 = l >> 4;
  const int li = l & 15;
  const int n0 = blockIdx.x << 5;
  const int wvb = wv << 10;                  // 1024 u16 per wave

  // W: lane l instr j -> row 4*(l>>3)+j, cols n0+(l&7)*4..+3
  const float* gW2 = W + (size_t)(4 * (l >> 3)) * Nw + n0 + (l & 7) * 4;
  const size_t stepW2 = (size_t)32 * Nw;
  // A: lane row wv*16+li, k-chunk g4*8 (direct to reg)
  const u16* gA2 = A + (size_t)(wv * 16 + li) * 4096 + g4 * 8;

  // pack offsets: n = (l&7)*4+c, k-chunk kc=(l>>3)>>1, klo=((l>>3)&1)*4
  // swizzle sw(n)=((n>>1)^(n>>2))&3; elem off = wvb + n*32 + ((kc^sw)<<3)+klo
  const int kc_  = (l >> 3) >> 1;
  const int klo_ = ((l >> 3) & 1) << 2;
  #define WO2(C_) (wvb + ((l & 7) * 4 + (C_)) * 32 +                           \
    ((kc_ ^ ((((((l & 7) * 4 + (C_)) >> 1) ^ (((l & 7) * 4 + (C_)) >> 2))) & 3)) << 3) + klo_)
  const int wo2_0 = WO2(0);
  const int wo2_1 = WO2(1);
  const int wo2_2 = WO2(2);
  const int wo2_3 = WO2(3);
  // read: n = ct*16+li -> sw(n)=sw(li)
  const int ro2 = wvb + li * 32 + ((g4 ^ (((li >> 1) ^ (li >> 2)) & 3)) << 3);

  f32x4 z4 = {0.f, 0.f, 0.f, 0.f};
  f32x4 acc0 = z4, acc1 = z4;
  f32x4 vs0, vs1, vs2, vs3;
  bf16x8 aS2, aC;

  // ---- prologue: tile0 -> regs -> buf0; issue tile1; wave-local drain ----
  WLOADS2(0)
  aC = aS2;
  WPACK2(0, lB0) WPACK2(1, lB0) WPACK2(2, lB0) WPACK2(3, lB0)
  WLOADS2(1)
  asm volatile("s_waitcnt lgkmcnt(0)" ::: "memory");

  // ---- main loop: ns=128, no barriers, 2-unrolled ----
  for (int st = 0; st < 128; st += 2) {
    GEMM2_STEP(st,     lB0, lB1)
    GEMM2_STEP(st + 1, lB1, lB0)
  }

  // fused epilogue: row = wv*16 + g4*4 + j, col = n0 + ct*16 + li
  const float b0v = bias[n0 + li];
  const float b1v = bias[n0 + 16 + li];
  #pragma unroll
  for (int j = 0; j < 4; ++j) {
    const int R = wv * 16 + g4 * 4 + j;
    float v0 = acc0[j] + b0v;
    float v1 = acc1[j] + b1v;
    v0 = v0 > 0.f ? v0 : 0.f;
    v1 = v1 > 0.f ? v1 : 0.f;
    if (WRITEF) {
      float* p = outf + (size_t)R * Nw + n0 + li;
      p[0]  = v0;
      p[16] = v1;
      p[NB * LATD]      = v0;
      p[NB * LATD + 16] = v1;
    } else {
      u16* p = outb + (size_t)R * Nw + n0 + li;
      p[0]  = f2b(v0);
      p[16] = f2b(v1);
    }
  }
}

// ---------- epilogue for GEMM12 ----------
__global__ void k_ep12(const float* __restrict__ Cs,
                       const float* __restrict__ b1, const float* __restrict__ b2,
                       u16* __restrict__ A3) {
  int i = blockIdx.x * 256 + threadIdx.x;
  if (i >= NB * H3) return;
  float mix = b1[i & (H3 - 1)];
  float v   = b2[i & (H3 - 1)];
  #pragma unroll 4
  for (int s = 0; s < 16; ++s)  mix += Cs[(size_t)s * (NB * H3) + i];
  #pragma unroll 4
  for (int s = 16; s < 32; ++s) v   += Cs[(size_t)s * (NB * H3) + i];
  mix = mix > 0.f ? mix : 0.f;
  v   = v   > 0.f ? v   : 0.f;
  A3[i] = f2b(v + mix);
}

extern "C" void kernel_launch(void* const* d_in, const int* in_sizes, int n_in,
                              void* d_out, int out_size, void* d_ws, size_t ws_size,
                              hipStream_t stream) {
  const int*   E    = (const int*)d_in[0];
  const float* X    = (const float*)d_in[1];
  const float* cls  = (const float*)d_in[2];
  const float* Wg1  = (const float*)d_in[3];
  const float* Wg2  = (const float*)d_in[4];
  const float* Wbox = (const float*)d_in[5];
  const float* bbox = (const float*)d_in[6];
  const float* Wlbl = (const float*)d_in[7];
  const float* blbl = (const float*)d_in[8];
  const float* Wd1  = (const float*)d_in[9];
  const float* bd1  = (const float*)d_in[10];
  const float* Wd2  = (const float*)d_in[11];
  const float* bd2  = (const float*)d_in[12];
  const float* Wd3  = (const float*)d_in[13];
  const float* bd3  = (const float*)d_in[14];
  const float* Wz   = (const float*)d_in[15];
  const float* bz   = (const float*)d_in[16];

  // workspace map (~45 MiB; ws ~1 GiB)
  char* ws = (char*)d_ws;
  int*   cnt  = (int*)  (ws + 0x000000);  // 256 KB (memset)
  int*   off  = (int*)  (ws + 0x040000);  // 256 KB
  int*   cur  = (int*)  (ws + 0x080000);  // 256 KB
  int*   csr  = (int*)  (ws + 0x0C0000);  // 1 MB
  float* S1   = (float*)(ws + 0x1C0000);  // 2 MB (fully overwritten)
  float* S2   = (float*)(ws + 0x3C0000);  // 2 MB (fully overwritten)
  float* Wc   = (float*)(ws + 0x5C0000);  // 512 B
  u16*   A3   = (u16*)  (ws + 0x5C1000);  // 512 KB
  u16*   A4   = (u16*)  (ws + 0x641000);  // 512 KB
  u16*   A5   = (u16*)  (ws + 0x6C1000);  // 512 KB
  u16*   Mbuf = (u16*)  (ws + 0x741000);  // 2 MB
  u16*   Abuf = (u16*)  (ws + 0x941000);  // ~2.02 MB
  float* Cslb = (float*)(ws + 0xB50000);  // 32 slabs x 1 MB

  hipMemsetAsync(cnt, 0, 0x40000, stream);
  k_hist   <<<NEDGE / 256, 256, 0, stream>>>(E, cnt, Wg1, Wg2, Wc);
  k_scan   <<<1, 1024, 0, stream>>>(cnt, off, cur);
  k_scatter<<<NEDGE / 256, 256, 0, stream>>>(E, cur, csr);
  k_gather <<<NTOT * 8 / 256, 256, 0, stream>>>(off, cnt, csr, X,  S1);
  k_gather <<<NTOT * 8 / 256, 256, 0, stream>>>(off, cnt, csr, S1, S2);
  k_nodes  <<<NTOT * 16 / 256, 256, 0, stream>>>(S2, Wc, X, Wbox, bbox, Wlbl, blbl,
                                                 cls, Abuf, Mbuf);

  // GEMM1+2 merged (z=0: Mbuf@Wd1 -> slabs 0..15; z=1: Abuf@Wd2 -> slabs 16..31)
  { dim3 g(16, 16, 2);
    k_gemm<<<g, 256, 0, stream>>>(Mbuf, Abuf, K1, K2, Wd1, Wd2, H3,
                                  512, 517, 32, 33, 16, Cslb); }
  k_ep12<<<NB * H3 / 256, 256, 0, stream>>>(Cslb, bd1, bd2, A3);

  // GEMM3: A4 = relu(A3 @ Wd3 + b3)  — full-K fused, no slabs
  k_gemm2<0><<<H3 / 32, 256, 0, stream>>>(A3, Wd3, H3, bd3, A4, nullptr);
  // GEMM4: A5 = relu(A4 @ Wd3 + b3)
  k_gemm2<0><<<H3 / 32, 256, 0, stream>>>(A4, Wd3, H3, bd3, A5, nullptr);
  // GEMM5: z = relu(A5 @ Wz + bz), both output halves fused
  k_gemm2<1><<<LATD / 32, 256, 0, stream>>>(A5, Wz, LATD, bz, nullptr,
                                            (float*)d_out);
}

// Round 6
// 291.715 us; speedup vs baseline: 1.3681x; 1.3681x over previous
//
#include <hip/hip_runtime.h>
#include <stdint.h>

typedef unsigned short u16;
typedef short bf16x8 __attribute__((ext_vector_type(8)));
typedef short bf16x4 __attribute__((ext_vector_type(4)));
typedef float f32x4 __attribute__((ext_vector_type(4)));

#define NTOT   65536
#define NB     64
#define NEDGE  262144
#define H3     4096
#define LATD   512
#define NCLS_  160
#define K1     16384
#define K2     16544   // NCLS + 1024*16

static __device__ __forceinline__ u16 f2b(float f) {   // fp32 -> bf16 RNE
  uint32_t x = __float_as_uint(f);
  return (u16)((x + 0x7FFFu + ((x >> 16) & 1u)) >> 16);
}

// ---------- CSR build: histogram (+ fused Wc = Wg1@Wg2 in block 0) ----------
__global__ void k_hist(const int* __restrict__ E, int* __restrict__ cnt,
                       const float* __restrict__ Wg1, const float* __restrict__ Wg2,
                       float* __restrict__ Wc) {
  int e = blockIdx.x * 256 + threadIdx.x;
  atomicAdd(&cnt[E[NEDGE + e]], 1);
  if (blockIdx.x == 0 && threadIdx.x < 128) {
    int c = threadIdx.x >> 4, h = threadIdx.x & 15;
    float acc = 0.f;
    for (int k = 0; k < 512; ++k) acc += Wg1[c * 512 + k] * Wg2[k * 16 + h];
    Wc[c * 16 + h] = acc;
  }
}

// ---------- exclusive scan of 65536 counts (single block, 1024 threads) ----------
__global__ __launch_bounds__(1024) void k_scan(const int* __restrict__ cnt,
                                               int* __restrict__ off,
                                               int* __restrict__ cur) {
  __shared__ int wsum[16];
  const int t = threadIdx.x;
  const int lane = t & 63, w = t >> 6;
  const int base = t << 6;                          // 64 bins per thread
  int s = 0;
  const int4* c4 = (const int4*)(cnt + base);
  #pragma unroll 4
  for (int i = 0; i < 16; ++i) { int4 v = c4[i]; s += v.x + v.y + v.z + v.w; }
  int sc = s;
  #pragma unroll
  for (int d = 1; d < 64; d <<= 1) {
    int u = __shfl_up(sc, d);
    if (lane >= d) sc += u;
  }
  if (lane == 63) wsum[w] = sc;
  __syncthreads();
  if (w == 0 && lane < 16) {
    int v = wsum[lane];
    #pragma unroll
    for (int d = 1; d < 16; d <<= 1) {
      int u = __shfl_up(v, d);
      if (lane >= d) v += u;
    }
    wsum[lane] = v;
  }
  __syncthreads();
  int run = (w == 0 ? 0 : wsum[w - 1]) + (sc - s);
  int4* o4 = (int4*)(off + base);
  int4* u4 = (int4*)(cur + base);
  #pragma unroll 4
  for (int i = 0; i < 16; ++i) {
    int4 v = c4[i];
    int4 r;
    r.x = run; run += v.x;
    r.y = run; run += v.y;
    r.z = run; run += v.z;
    r.w = run; run += v.w;
    o4[i] = r; u4[i] = r;
  }
}

// ---------- scatter edges into CSR ----------
__global__ void k_scatter(const int* __restrict__ E, int* __restrict__ cur,
                          int* __restrict__ csr) {
  int e = blockIdx.x * 256 + threadIdx.x;
  int p = atomicAdd(&cur[E[NEDGE + e]], 1);
  csr[p] = E[e];
}

// ---------- atomic-free segment sum: Out[n][c] = sum_j In[csr[j]][c] ----------
__global__ void k_gather(const int* __restrict__ off, const int* __restrict__ cnt,
                         const int* __restrict__ csr, const float* __restrict__ In,
                         float* __restrict__ Out) {
  int t = blockIdx.x * 256 + threadIdx.x;           // NTOT*8 threads
  int n = t >> 3, c = t & 7;
  int b = off[n], e = b + cnt[n];
  float acc = 0.f;
  for (int j = b; j < e; ++j) acc += In[(size_t)csr[j] * 8 + c];
  Out[(size_t)n * 8 + c] = acc;
}

// ---------- fused gather2 + per-node features (S2 never materialized) ----------
// thread (n,c): S2[n][c] = segment-sum over csr; 8-lane shfl broadcast of the
// row; each thread emits h=c and h=c+8 of gcn-out (Abuf) and mix (Mbuf).
__global__ void k_gnodes(const int* __restrict__ off, const int* __restrict__ cnt,
                         const int* __restrict__ csr, const float* __restrict__ S1,
                         const float* __restrict__ Wc, const float* __restrict__ X,
                         const float* __restrict__ Wbox, const float* __restrict__ bbox,
                         const float* __restrict__ Wlbl, const float* __restrict__ blbl,
                         const float* __restrict__ cls,
                         u16* __restrict__ Abuf, u16* __restrict__ Mbuf) {
  int t = blockIdx.x * 256 + threadIdx.x;           // NTOT*8 threads
  if (t < NB * NCLS_) {
    int m = t / NCLS_, i = t - m * NCLS_;
    Abuf[(size_t)m * K2 + i] = f2b(cls[t]);
  }
  int n = t >> 3, c = t & 7;
  int b = off[n], e = b + cnt[n];
  float acc = 0.f;
  for (int j = b; j < e; ++j) acc += S1[(size_t)csr[j] * 8 + c];
  const int l = threadIdx.x & 63;
  const int gbase = l & 56;
  float xg0 = 0.f, xg1 = 0.f;
  #pragma unroll
  for (int cc = 0; cc < 8; ++cc) {
    float v = __shfl(acc, gbase | cc, 64);
    xg0 += v * Wc[cc * 16 + c];
    xg1 += v * Wc[cc * 16 + 8 + c];
  }
  int m = n >> 10, nl = n & 1023;
  u16* ab = Abuf + (size_t)m * K2 + 160 + nl * 16 + c;
  ab[0] = f2b(xg0);
  ab[8] = f2b(xg1);
  const float* xr = X + (size_t)n * 8;
  float box0 = bbox[c], box1 = bbox[8 + c];
  #pragma unroll
  for (int cc = 0; cc < 7; ++cc) {
    float xv = xr[1 + cc];
    box0 += xv * Wbox[cc * 16 + c];
    box1 += xv * Wbox[cc * 16 + 8 + c];
  }
  box0 = box0 > 0.f ? box0 : 0.f;
  box1 = box1 > 0.f ? box1 : 0.f;
  float x0 = xr[0];
  float lb0 = x0 * Wlbl[c] + blbl[c];
  float lb1 = x0 * Wlbl[8 + c] + blbl[8 + c];
  lb0 = lb0 > 0.f ? lb0 : 0.f;
  lb1 = lb1 > 0.f ? lb1 : 0.f;
  u16* mb = Mbuf + (size_t)m * K1 + nl * 16 + c;
  mb[0] = f2b(box0 + lb0);
  mb[8] = f2b(box1 + lb1);
}

// ---------- GEMM: slab[y] = A(bf16)[64,K] @ W(fp32->bf16)[K,BN=256] ----------
// r3 form (best measured). GEMM12 consumption is pinned at ~3.25 TB/s across
// all schedule variants (r0-r5) = the measured chip read-return ceiling
// (m13 copy 6.29 TB/s combined => ~3.15 read-side; fill write-only 6.7).
// 514 MB / 3.25 TB/s = 158 us floor -> this kernel is at its roofline.
#define CVTPK(dst, lo, hi) \
  asm("v_cvt_pk_bf16_f32 %0, %1, %2" : "=v"(dst) : "v"(lo), "v"(hi))

#define MFMA_BF16 __builtin_amdgcn_mfma_f32_16x16x32_bf16

#define WPACK(I2, WwR)                                                         \
  { const int n_ = (l << 2) + (I2);                                            \
    const int sw_ = ((n_ >> 1) ^ (n_ >> 2)) & 3;                               \
    uint32_t q0, q1, q2, q3;                                                   \
    CVTPK(q0, ws0[I2], ws1[I2]);                                               \
    CVTPK(q1, ws2[I2], ws3[I2]);                                               \
    CVTPK(q2, ws4[I2], ws5[I2]);                                               \
    CVTPK(q3, ws6[I2], ws7[I2]);                                               \
    uint4 pk_ = {q0, q1, q2, q3};                                              \
    *(uint4*)(&WwR[n_ * 32 + ((wv ^ sw_) << 3)]) = pk_; }

#define WLOADS(II)                                                             \
  { const float* gw_ = gW + (size_t)(II) * stepW;                              \
    ws0 = *(const f32x4*)(gw_);                                                \
    ws1 = *(const f32x4*)(gw_ + Nw);                                           \
    ws2 = *(const f32x4*)(gw_ + 2 * Nw);                                       \
    ws3 = *(const f32x4*)(gw_ + 3 * Nw);                                       \
    ws4 = *(const f32x4*)(gw_ + 4 * Nw);                                       \
    ws5 = *(const f32x4*)(gw_ + 5 * Nw);                                       \
    ws6 = *(const f32x4*)(gw_ + 6 * Nw);                                       \
    ws7 = *(const f32x4*)(gw_ + 7 * Nw);                                       \
    aS  = *(const int4*)(gA + (size_t)(II) * 32); }

#define GEMM_STEP(ST, ArD, WrD, AwR, WwR)                                      \
  {                                                                            \
    bf16x8 a0 = *(const bf16x8*)(&ArD[foA]);                                   \
    bf16x8 a1 = *(const bf16x8*)(&ArD[foA + 512]);                             \
    bf16x8 a2 = *(const bf16x8*)(&ArD[foA + 1024]);                            \
    bf16x8 a3 = *(const bf16x8*)(&ArD[foA + 1536]);                            \
    bf16x8 b0 = *(const bf16x8*)(&WrD[foB]);                                   \
    bf16x8 b1 = *(const bf16x8*)(&WrD[foB + 512]);                             \
    bf16x8 b2 = *(const bf16x8*)(&WrD[foB + 1024]);                            \
    bf16x8 b3 = *(const bf16x8*)(&WrD[foB + 1536]);                            \
    *(int4*)(&AwR[t * 8]) = aS;                                                \
    WPACK(0, WwR) WPACK(1, WwR) WPACK(2, WwR) WPACK(3, WwR)                    \
    { const int ii = (ST) + 2 < ns ? (ST) + 2 : ns - 1;                        \
      WLOADS(ii) }                                                             \
    acc00 = MFMA_BF16(a0, b0, acc00, 0, 0, 0);                                 \
    acc01 = MFMA_BF16(a0, b1, acc01, 0, 0, 0);                                 \
    acc02 = MFMA_BF16(a0, b2, acc02, 0, 0, 0);                                 \
    acc03 = MFMA_BF16(a0, b3, acc03, 0, 0, 0);                                 \
    acc10 = MFMA_BF16(a1, b0, acc10, 0, 0, 0);                                 \
    acc11 = MFMA_BF16(a1, b1, acc11, 0, 0, 0);                                 \
    acc12 = MFMA_BF16(a1, b2, acc12, 0, 0, 0);                                 \
    acc13 = MFMA_BF16(a1, b3, acc13, 0, 0, 0);                                 \
    acc20 = MFMA_BF16(a2, b0, acc20, 0, 0, 0);                                 \
    acc21 = MFMA_BF16(a2, b1, acc21, 0, 0, 0);                                 \
    acc22 = MFMA_BF16(a2, b2, acc22, 0, 0, 0);                                 \
    acc23 = MFMA_BF16(a2, b3, acc23, 0, 0, 0);                                 \
    acc30 = MFMA_BF16(a3, b0, acc30, 0, 0, 0);                                 \
    acc31 = MFMA_BF16(a3, b1, acc31, 0, 0, 0);                                 \
    acc32 = MFMA_BF16(a3, b2, acc32, 0, 0, 0);                                 \
    acc33 = MFMA_BF16(a3, b3, acc33, 0, 0, 0);                                 \
    asm volatile("s_waitcnt lgkmcnt(0)" ::: "memory");                         \
    __builtin_amdgcn_s_barrier();                                              \
    asm volatile("" ::: "memory");                                             \
  }

__global__ __launch_bounds__(256) void k_gemm(
    const u16* __restrict__ A0, const u16* __restrict__ A1, int lda0, int lda1,
    const float* __restrict__ W0, const float* __restrict__ W1, int Nw,
    int tot0, int tot1, int per0, int per1, int slabBase1,
    float* __restrict__ Cs)
{
  __shared__ u16 lA0[2048];     // A: 64 rows x 32 k bf16, 16B-chunk XOR swizzle
  __shared__ u16 lA1[2048];
  __shared__ u16 lW0[8192];     // W^T: [n=256][k=32] bf16, sw(n) XOR on k-chunks
  __shared__ u16 lW1[8192];

  const u16* A; int lda; const float* W; int tot, per, slab;
  if (blockIdx.z == 0) { A = A0; lda = lda0; W = W0; tot = tot0; per = per0; slab = blockIdx.y; }
  else                 { A = A1; lda = lda1; W = W1; tot = tot1; per = per1; slab = slabBase1 + blockIdx.y; }

  const int n0  = blockIdx.x << 8;                  // 256-col tiles
  const int sp0 = blockIdx.y * per;
  int ns = tot - sp0; if (ns > per) ns = per;
  if (ns <= 0) return;
  const int t  = threadIdx.x;
  const int l  = t & 63;
  const int wv = t >> 6;

  // A staging: thread t -> row t>>2, 16B chunk (t&3)^swA(row); LDS linear t*8
  const int rA  = t >> 2;
  const int cAg = (t & 3) ^ ((rA >> 1) & 3);
  const u16* gA = A + (size_t)rA * lda + cAg * 8 + (size_t)sp0 * 32;

  // W staging: wave wv owns k-rows 8wv..8wv+7; lane l covers 16B at col l*4
  const float* gW = W + (size_t)(sp0 * 32 + wv * 8) * Nw + n0 + l * 4;
  const size_t stepW = (size_t)32 * Nw;

  // fragment read offsets (elements)
  const int g4 = l >> 4;
  const int li = l & 15;
  const int foA = li * 32 + ((g4 ^ ((li >> 1) & 3)) << 3);               // + rt*512
  const int foB = wv * 2048 + li * 32 +
                  ((g4 ^ (((li >> 1) ^ (li >> 2)) & 3)) << 3);           // + ct*512

  f32x4 z4 = {0.f, 0.f, 0.f, 0.f};
  f32x4 acc00 = z4, acc01 = z4, acc02 = z4, acc03 = z4;
  f32x4 acc10 = z4, acc11 = z4, acc12 = z4, acc13 = z4;
  f32x4 acc20 = z4, acc21 = z4, acc22 = z4, acc23 = z4;
  f32x4 acc30 = z4, acc31 = z4, acc32 = z4, acc33 = z4;

  f32x4 ws0, ws1, ws2, ws3, ws4, ws5, ws6, ws7;
  int4 aS;

  // ---- prologue: tile0 -> regs -> buf0; issue tile1; barrier ----
  WLOADS(0)
  *(int4*)(&lA0[t * 8]) = aS;
  WPACK(0, lW0) WPACK(1, lW0) WPACK(2, lW0) WPACK(3, lW0)
  { const int i1 = 1 < ns ? 1 : 0;
    WLOADS(i1) }
  asm volatile("s_waitcnt lgkmcnt(0)" ::: "memory");
  __builtin_amdgcn_s_barrier();
  asm volatile("" ::: "memory");

  // ---- main loop: 2-unrolled for static buffer names ----
  int st = 0;
  for (; st + 2 <= ns; st += 2) {
    GEMM_STEP(st,     lA0, lW0, lA1, lW1)
    GEMM_STEP(st + 1, lA1, lW1, lA0, lW0)
  }
  if (st < ns) {
    GEMM_STEP(st, lA0, lW0, lA1, lW1)
  }

  // store: row = rt*16 + g4*4 + j, col = n0 + wv*64 + ct*16 + li
  float* base = Cs + (size_t)slab * NB * Nw + n0 + wv * 64 + li;
  #pragma unroll
  for (int j = 0; j < 4; ++j) {
    float* r0 = base + (size_t)(g4 * 4 + j) * Nw;
    r0[0]  = acc00[j];
    r0[16] = acc01[j];
    r0[32] = acc02[j];
    r0[48] = acc03[j];
    float* r1 = r0 + 16 * Nw;
    r1[0]  = acc10[j];
    r1[16] = acc11[j];
    r1[32] = acc12[j];
    r1[48] = acc13[j];
    float* r2 = r0 + 32 * Nw;
    r2[0]  = acc20[j];
    r2[16] = acc21[j];
    r2[32] = acc22[j];
    r2[48] = acc23[j];
    float* r3 = r0 + 48 * Nw;
    r3[0]  = acc30[j];
    r3[16] = acc31[j];
    r3[32] = acc32[j];
    r3[48] = acc33[j];
  }
}

// ---------- epilogues ----------
__global__ void k_ep12(const float* __restrict__ Cs,
                       const float* __restrict__ b1, const float* __restrict__ b2,
                       u16* __restrict__ A3) {
  int i = blockIdx.x * 256 + threadIdx.x;
  if (i >= NB * H3) return;
  float mix = b1[i & (H3 - 1)];
  float v   = b2[i & (H3 - 1)];
  #pragma unroll 4
  for (int s = 0; s < 16; ++s)  mix += Cs[(size_t)s * (NB * H3) + i];
  #pragma unroll 4
  for (int s = 16; s < 32; ++s) v   += Cs[(size_t)s * (NB * H3) + i];
  mix = mix > 0.f ? mix : 0.f;
  v   = v   > 0.f ? v   : 0.f;
  A3[i] = f2b(v + mix);
}

__global__ void k_ep(const float* __restrict__ Cs, int nslab, int slabElems,
                     const float* __restrict__ bias, u16* __restrict__ outb,
                     int colmask, int total) {
  int i = blockIdx.x * 256 + threadIdx.x;
  if (i >= total) return;
  float v = bias[i & colmask];
  #pragma unroll 4
  for (int s = 0; s < nslab; ++s) v += Cs[(size_t)s * slabElems + i];
  v = v > 0.f ? v : 0.f;
  outb[i] = f2b(v);
}

__global__ void k_ep5(const float* __restrict__ Cs, int nslab,
                      const float* __restrict__ bz, float* __restrict__ out) {
  int i = blockIdx.x * 256 + threadIdx.x;
  if (i >= NB * LATD) return;
  float v = bz[i & 511];
  #pragma unroll 4
  for (int s = 0; s < nslab; ++s) v += Cs[(size_t)s * (NB * LATD) + i];
  v = v > 0.f ? v : 0.f;
  out[i] = v;
  out[NB * LATD + i] = v;   // z_mean and z_logvar identical
}

extern "C" void kernel_launch(void* const* d_in, const int* in_sizes, int n_in,
                              void* d_out, int out_size, void* d_ws, size_t ws_size,
                              hipStream_t stream) {
  const int*   E    = (const int*)d_in[0];
  const float* X    = (const float*)d_in[1];
  const float* cls  = (const float*)d_in[2];
  const float* Wg1  = (const float*)d_in[3];
  const float* Wg2  = (const float*)d_in[4];
  const float* Wbox = (const float*)d_in[5];
  const float* bbox = (const float*)d_in[6];
  const float* Wlbl = (const float*)d_in[7];
  const float* blbl = (const float*)d_in[8];
  const float* Wd1  = (const float*)d_in[9];
  const float* bd1  = (const float*)d_in[10];
  const float* Wd2  = (const float*)d_in[11];
  const float* bd2  = (const float*)d_in[12];
  const float* Wd3  = (const float*)d_in[13];
  const float* bd3  = (const float*)d_in[14];
  const float* Wz   = (const float*)d_in[15];
  const float* bz   = (const float*)d_in[16];

  // workspace map (~45 MiB; ws ~1 GiB)
  char* ws = (char*)d_ws;
  int*   cnt  = (int*)  (ws + 0x000000);  // 256 KB (memset)
  int*   off  = (int*)  (ws + 0x040000);  // 256 KB
  int*   cur  = (int*)  (ws + 0x080000);  // 256 KB
  int*   csr  = (int*)  (ws + 0x0C0000);  // 1 MB
  float* S1   = (float*)(ws + 0x1C0000);  // 2 MB (fully overwritten)
  float* Wc   = (float*)(ws + 0x5C0000);  // 512 B
  u16*   A3   = (u16*)  (ws + 0x5C1000);  // 512 KB
  u16*   A4   = (u16*)  (ws + 0x641000);  // 512 KB
  u16*   A5   = (u16*)  (ws + 0x6C1000);  // 512 KB
  u16*   Mbuf = (u16*)  (ws + 0x741000);  // 2 MB
  u16*   Abuf = (u16*)  (ws + 0x941000);  // ~2.02 MB
  float* Cslb = (float*)(ws + 0xB50000);  // 32 slabs x 1 MB

  hipMemsetAsync(cnt, 0, 0x40000, stream);
  k_hist   <<<NEDGE / 256, 256, 0, stream>>>(E, cnt, Wg1, Wg2, Wc);
  k_scan   <<<1, 1024, 0, stream>>>(cnt, off, cur);
  k_scatter<<<NEDGE / 256, 256, 0, stream>>>(E, cur, csr);
  k_gather <<<NTOT * 8 / 256, 256, 0, stream>>>(off, cnt, csr, X, S1);
  k_gnodes <<<NTOT * 8 / 256, 256, 0, stream>>>(off, cnt, csr, S1, Wc, X,
                                                Wbox, bbox, Wlbl, blbl, cls,
                                                Abuf, Mbuf);

  // GEMM1+2 merged (z=0: Mbuf@Wd1 -> slabs 0..15; z=1: Abuf@Wd2 -> slabs 16..31)
  { dim3 g(16, 16, 2);
    k_gemm<<<g, 256, 0, stream>>>(Mbuf, Abuf, K1, K2, Wd1, Wd2, H3,
                                  512, 517, 32, 33, 16, Cslb); }
  k_ep12<<<NB * H3 / 256, 256, 0, stream>>>(Cslb, bd1, bd2, A3);

  // GEMM3: A4 = relu(A3 @ Wd3 + b3)   (16 slabs)
  { dim3 g(16, 16, 1);
    k_gemm<<<g, 256, 0, stream>>>(A3, A3, H3, H3, Wd3, Wd3, H3,
                                  128, 128, 8, 8, 0, Cslb); }
  k_ep<<<NB * H3 / 256, 256, 0, stream>>>(Cslb, 16, NB * H3, bd3, A4, H3 - 1, NB * H3);

  // GEMM4: A5 = relu(A4 @ Wd3 + b3)   (16 slabs)
  { dim3 g(16, 16, 1);
    k_gemm<<<g, 256, 0, stream>>>(A4, A4, H3, H3, Wd3, Wd3, H3,
                                  128, 128, 8, 8, 0, Cslb); }
  k_ep<<<NB * H3 / 256, 256, 0, stream>>>(Cslb, 16, NB * H3, bd3, A5, H3 - 1, NB * H3);

  // GEMM5: z = relu(A5 @ Wz + bz), written to both output halves
  { dim3 g(2, 32, 1);
    k_gemm<<<g, 256, 0, stream>>>(A5, A5, H3, H3, Wz, Wz, LATD,
                                  128, 128, 4, 4, 0, Cslb); }
  k_ep5<<<NB * LATD / 256, 256, 0, stream>>>(Cslb, 32, bz, (float*)d_out);
}